// Round 12
// baseline (929.725 us; speedup 1.0000x reference)
//
#include <hip/hip_runtime.h>
#include <hip/hip_bf16.h>

typedef __attribute__((ext_vector_type(8))) short bf16x8;
typedef __attribute__((ext_vector_type(4))) float f32x4;

static __device__ __forceinline__ void stf(float* p, size_t i, float v) { p[i] = v; }
static __device__ __forceinline__ void stf(__hip_bfloat16* p, size_t i, float v) { p[i] = __float2bfloat16(v); }

static __device__ __forceinline__ void gload_lds16(const void* g, void* l) {
  __builtin_amdgcn_global_load_lds((const __attribute__((address_space(1))) void*)g,
                                   (__attribute__((address_space(3))) void*)l, 16, 0, 0);
}
static __device__ __forceinline__ void barrier() {
  __builtin_amdgcn_sched_barrier(0);
  __builtin_amdgcn_s_barrier();
  __builtin_amdgcn_sched_barrier(0);
}

// ---------- weight transpose + bf16 convert: W[K][N] f32 -> WT[N][K] bf16 ----------
__global__ void wt_kernel(const float* __restrict__ W, __hip_bfloat16* __restrict__ WT, int K, int N) {
  __shared__ float tile[32][33];
  const int kb = blockIdx.y * 32, nb = blockIdx.x * 32;
  const int tx = threadIdx.x & 31, ty = threadIdx.x >> 5;
#pragma unroll
  for (int i = 0; i < 4; ++i)
    tile[ty + i * 8][tx] = W[(size_t)(kb + ty + i * 8) * N + nb + tx];
  __syncthreads();
#pragma unroll
  for (int i = 0; i < 4; ++i)
    WT[(size_t)(nb + ty + i * 8) * K + kb + tx] = __float2bfloat16(tile[tx][ty + i * 8]);
}

// ---------- conv prep ----------
__global__ void convprep_kernel(const float* __restrict__ w, const float* __restrict__ bng,
                                const float* __restrict__ bnb, const float* __restrict__ bnm,
                                const float* __restrict__ bnv, float* __restrict__ wT,
                                float* __restrict__ st) {
  const int i = blockIdx.x * 256 + threadIdx.x;
  if (i < 576 * 9) {
    const int t = i / 576, c = i - t * 576;
    wT[i] = w[c * 9 + t];
  }
  if (i < 576) {
    const float s = rsqrtf(bnv[i] + 1e-5f) * bng[i];
    st[i] = s;
    st[576 + i] = bnb[i] - bnm[i] * s;
  }
}

// ---------- fused LN -> bf16 ----------
__global__ void ln_bf16_kernel(const float* __restrict__ x, const float* __restrict__ g,
                               const float* __restrict__ b, __hip_bfloat16* __restrict__ y) {
  const int row = blockIdx.x * 4 + (threadIdx.x >> 6);
  const int lane = threadIdx.x & 63;
  const float* p = x + (size_t)row * 576;
  float vals[9];
  float s = 0.f, ss = 0.f;
#pragma unroll
  for (int i = 0; i < 9; ++i) {
    float v = p[lane + i * 64];
    vals[i] = v; s += v; ss += v * v;
  }
#pragma unroll
  for (int o = 32; o; o >>= 1) { s += __shfl_down(s, o); ss += __shfl_down(ss, o); }
  s = __shfl(s, 0); ss = __shfl(ss, 0);
  const float m = s * (1.f / 576.f);
  const float rstd = rsqrtf(ss * (1.f / 576.f) - m * m + 1e-5f);
  __hip_bfloat16* q = y + (size_t)row * 576;
#pragma unroll
  for (int i = 0; i < 9; ++i) {
    const int c = lane + i * 64;
    q[c] = __float2bfloat16((vals[i] - m) * rstd * g[c] + b[c]);
  }
}

// ---------- DIRECT-GLOBAL MFMA GEMM: no LDS, no barriers, no staging ----------
// Block 128x192 = 2x2 waves, wave tile 64x96 (MI=4, NI=6). Each bf16x8 frag
// load is a dense global read (16 lanes x full 128B line). A is L3-resident,
// B is L2-resident; paired waves share lines via L1. Waves drift freely ->
// latency hidden by TLP+ILP instead of the staged-LDS barrier spine that
// R6-R10 showed to be the invariant wall. K ascending in 32-chunks ->
// bit-identical accumulation vs staged kernels.
// EPI: 0 none, 1 +res, 2 exact GELU
template <int EPI, typename TO>
__global__ __launch_bounds__(256) void gemm_direct(
    const __hip_bfloat16* __restrict__ A, const __hip_bfloat16* __restrict__ BT,
    const float* __restrict__ bias, const float* __restrict__ res, TO* __restrict__ C,
    int M, int N, int K) {
  const int t = threadIdx.x, lane = t & 63, w = t >> 6;
  const int nwg = gridDim.x;
  const int qq = nwg >> 3, r8 = nwg & 7;
  const int xcd = blockIdx.x & 7, lidx = blockIdx.x >> 3;
  const int wgid = (xcd < r8 ? xcd * (qq + 1) : r8 * (qq + 1) + (xcd - r8) * qq) + lidx;
  const int nx = N / 192;
  const int bm = (wgid / nx) * 128, bn = (wgid % nx) * 192;
  const int wm = (w >> 1) * 64, wn = (w & 1) * 96;
  const int l15 = lane & 15, l4 = lane >> 4;

  f32x4 acc[4][6];
#pragma unroll
  for (int mi = 0; mi < 4; ++mi)
#pragma unroll
    for (int ni = 0; ni < 6; ++ni) acc[mi][ni] = (f32x4){0.f, 0.f, 0.f, 0.f};

  const __hip_bfloat16* pa[4];
  const __hip_bfloat16* pb[6];
#pragma unroll
  for (int mi = 0; mi < 4; ++mi)
    pa[mi] = A + (size_t)(bm + wm + mi * 16 + l15) * K + l4 * 8;
#pragma unroll
  for (int ni = 0; ni < 6; ++ni)
    pb[ni] = BT + (size_t)(bn + wn + ni * 16 + l15) * K + l4 * 8;

  const int nk = K >> 5;
#pragma unroll 2
  for (int kt = 0; kt < nk; ++kt) {
    bf16x8 a[4], b[6];
    const int ko = kt * 32;
#pragma unroll
    for (int mi = 0; mi < 4; ++mi) a[mi] = *(const bf16x8*)(pa[mi] + ko);
#pragma unroll
    for (int ni = 0; ni < 6; ++ni) b[ni] = *(const bf16x8*)(pb[ni] + ko);
#pragma unroll
    for (int mi = 0; mi < 4; ++mi)
#pragma unroll
      for (int ni = 0; ni < 6; ++ni)
        acc[mi][ni] = __builtin_amdgcn_mfma_f32_16x16x32_bf16(a[mi], b[ni], acc[mi][ni], 0, 0, 0);
  }

#pragma unroll
  for (int mi = 0; mi < 4; ++mi) {
    const int mrow = bm + wm + mi * 16 + l4 * 4;
#pragma unroll
    for (int ni = 0; ni < 6; ++ni) {
      const int col = bn + wn + ni * 16 + l15;
      const float bv = bias[col];
#pragma unroll
      for (int r2 = 0; r2 < 4; ++r2) {
        const size_t idx = (size_t)(mrow + r2) * N + col;
        float v = acc[mi][ni][r2] + bv;
        if (EPI == 1) v += res[idx];
        if (EPI == 2) v = 0.5f * v * (1.0f + erff(v * 0.70710678118654752f));
        stf(C, idx, v);
      }
    }
  }
}

// ---------- staged GEMM (R9 coarse counted-vmcnt) — control, used for proj ----------
template <int EPI, typename TO>
__global__ __launch_bounds__(512, 1) void gemm_bt(
    const __hip_bfloat16* __restrict__ A, const __hip_bfloat16* __restrict__ BT,
    const float* __restrict__ bias, const float* __restrict__ res, TO* __restrict__ C,
    int M, int N, int K) {
  constexpr int BM = 256, BN = 192;
  constexpr int MI = 8, NI = 3;
  constexpr int AI = 4, BI = 3;
  __shared__ __hip_bfloat16 sA[2][BM * 64];
  __shared__ __hip_bfloat16 sB[2][BN * 64];
  const int t = threadIdx.x;
  const int lane = t & 63;
  const int w = t >> 6;
  const int nwg = gridDim.x;
  const int qq = nwg >> 3, r = nwg & 7;
  const int xcd = blockIdx.x & 7, lidx = blockIdx.x >> 3;
  const int wgid = (xcd < r ? xcd * (qq + 1) : r * (qq + 1) + (xcd - r) * qq) + lidx;
  const int nx = N / BN;
  const int bm = (wgid / nx) * BM, bn = (wgid % nx) * BN;
  const int wm = (w >> 2) * 128, wn = (w & 3) * 48;
  const int l15 = lane & 15, l4 = lane >> 4;

  f32x4 acc[MI][NI];
#pragma unroll
  for (int mi = 0; mi < MI; ++mi)
#pragma unroll
    for (int ni = 0; ni < NI; ++ni) acc[mi][ni] = (f32x4){0.f, 0.f, 0.f, 0.f};

  const int wave_base = t & ~63;

  auto stage = [&](int buf, int kt) {
    const int k0 = kt << 6;
#pragma unroll
    for (int i = 0; i < AI; ++i) {
      const int slot = i * 512 + t;
      const int row = slot >> 3, kst = slot & 7;
      const int ksrc = kst ^ (row & 7);
      gload_lds16(A + (size_t)(bm + row) * K + k0 + ksrc * 8, sA[buf] + (i * 512 + wave_base) * 8);
    }
#pragma unroll
    for (int i = 0; i < BI; ++i) {
      const int slot = i * 512 + t;
      const int row = slot >> 3, kst = slot & 7;
      const int ksrc = kst ^ (row & 7);
      gload_lds16(BT + (size_t)(bn + row) * K + k0 + ksrc * 8, sB[buf] + (i * 512 + wave_base) * 8);
    }
  };

  auto compute = [&](int buf) {
    const __hip_bfloat16* pA = sA[buf];
    const __hip_bfloat16* pB = sB[buf];
#pragma unroll
    for (int kb = 0; kb < 2; ++kb) {
      bf16x8 a[MI], b[NI];
      const int kblk = kb * 4 + l4;
#pragma unroll
      for (int mi = 0; mi < MI; ++mi) {
        const int row = wm + mi * 16 + l15;
        a[mi] = *(const bf16x8*)(pA + row * 64 + ((kblk ^ (row & 7)) * 8));
      }
#pragma unroll
      for (int ni = 0; ni < NI; ++ni) {
        const int row = wn + ni * 16 + l15;
        b[ni] = *(const bf16x8*)(pB + row * 64 + ((kblk ^ (row & 7)) * 8));
      }
#pragma unroll
      for (int mi = 0; mi < MI; ++mi)
#pragma unroll
        for (int ni = 0; ni < NI; ++ni)
          acc[mi][ni] = __builtin_amdgcn_mfma_f32_16x16x32_bf16(a[mi], b[ni], acc[mi][ni], 0, 0, 0);
    }
  };

  const int nt = K >> 6;
  stage(0, 0);
  stage(1, 1);
  int cur = 0;
  for (int tt = 0; tt < nt; ++tt) {
    if (tt < nt - 1) asm volatile("s_waitcnt vmcnt(7)" ::: "memory");
    else             asm volatile("s_waitcnt vmcnt(0)" ::: "memory");
    barrier();
    compute(cur);
    if (tt + 2 < nt) {
      barrier();
      stage(cur, tt + 2);
    }
    cur ^= 1;
  }

#pragma unroll
  for (int mi = 0; mi < MI; ++mi) {
    const int mrow = bm + wm + mi * 16 + l4 * 4;
#pragma unroll
    for (int ni = 0; ni < NI; ++ni) {
      const int col = bn + wn + ni * 16 + l15;
      const float bv = bias[col];
#pragma unroll
      for (int r2 = 0; r2 < 4; ++r2) {
        const size_t idx = (size_t)(mrow + r2) * N + col;
        float v = acc[mi][ni][r2] + bv;
        if (EPI == 1) v += res[idx];
        if (EPI == 2) v = 0.5f * v * (1.0f + erff(v * 0.70710678118654752f));
        stf(C, idx, v);
      }
    }
  }
}

// ---------- MFMA windowed attention: 1 wave per (window, head) ----------
__global__ __launch_bounds__(64) void attn_mfma_kernel(
    const __hip_bfloat16* __restrict__ qkv, const float* __restrict__ biases,
    __hip_bfloat16* __restrict__ o) {
  __shared__ __hip_bfloat16 sQK[2][64][40];
  __shared__ __hip_bfloat16 sVT[32][72];
  __hip_bfloat16 (*sP)[72] = (__hip_bfloat16(*)[72])(&sQK[0][0][0]);

  const int wid  = blockIdx.x / 18;
  const int head = blockIdx.x - wid * 18;
  const int b  = wid >> 4;
  const int wi = wid & 15;
  const int wh = wi >> 2, wwc = wi & 3;
  const int lane = threadIdx.x;
  const int l15 = lane & 15, l4 = lane >> 4;

  {
    const __hip_bfloat16* basep = qkv + (size_t)head * 96;
    for (int idx = lane; idx < 49 * 12; idx += 64) {
      const int tkn = idx / 12, part = idx - tkn * 12;
      const int r = tkn / 7, c = tkn - r * 7;
      const size_t row = (size_t)b * 784 + (size_t)((wh * 7 + r) * 28 + wwc * 7 + c);
      bf16x8 v = *(const bf16x8*)(basep + row * 1728 + part * 8);
      if (part < 4)      *(bf16x8*)&sQK[0][tkn][part * 8] = v;
      else if (part < 8) *(bf16x8*)&sQK[1][tkn][(part - 4) * 8] = v;
      else {
        const int d0 = (part - 8) * 8;
        const short* sv = (const short*)&v;
#pragma unroll
        for (int e = 0; e < 8; ++e)
          sVT[d0 + e][tkn] = *(const __hip_bfloat16*)&sv[e];
      }
    }
    for (int idx = lane; idx < 32 * 15; idx += 64) {
      const int d = idx / 15, tt = 49 + (idx - d * 15);
      sVT[d][tt] = __float2bfloat16(0.0f);
    }
  }
  __syncthreads();

  f32x4 acc[4][4];
#pragma unroll
  for (int mi = 0; mi < 4; ++mi)
#pragma unroll
    for (int ni = 0; ni < 4; ++ni) acc[mi][ni] = (f32x4){0.f, 0.f, 0.f, 0.f};
  {
    bf16x8 aq[4], bk[4];
#pragma unroll
    for (int mi = 0; mi < 4; ++mi) aq[mi] = *(const bf16x8*)&sQK[0][mi * 16 + l15][l4 * 8];
#pragma unroll
    for (int ni = 0; ni < 4; ++ni) bk[ni] = *(const bf16x8*)&sQK[1][ni * 16 + l15][l4 * 8];
#pragma unroll
    for (int mi = 0; mi < 4; ++mi)
#pragma unroll
      for (int ni = 0; ni < 4; ++ni)
        acc[mi][ni] = __builtin_amdgcn_mfma_f32_16x16x32_bf16(aq[mi], bk[ni], acc[mi][ni], 0, 0, 0);
  }
  __syncthreads();

  const float scale = 0.17677669529663687f;
  const float* btab = biases + head * 49;
#pragma unroll
  for (int mi = 0; mi < 4; ++mi) {
#pragma unroll
    for (int rr = 0; rr < 4; ++rr) {
      const int i = mi * 16 + l4 * 4 + rr;
      const int ic = i < 49 ? i : 0;
      const int ri = ic / 7, ci = ic - ri * 7;
      float s[4];
#pragma unroll
      for (int ni = 0; ni < 4; ++ni) {
        const int j = ni * 16 + l15;
        if (j < 49) {
          const int rj = j / 7, cj = j - rj * 7;
          s[ni] = acc[mi][ni][rr] * scale + btab[__builtin_abs(ri - rj) * 7 + __builtin_abs(ci - cj)];
        } else {
          s[ni] = -1e30f;
        }
      }
      float m = fmaxf(fmaxf(s[0], s[1]), fmaxf(s[2], s[3]));
#pragma unroll
      for (int d = 1; d < 16; d <<= 1) m = fmaxf(m, __shfl_xor(m, d));
      float sum = 0.f;
#pragma unroll
      for (int ni = 0; ni < 4; ++ni) { s[ni] = __expf(s[ni] - m); sum += s[ni]; }
#pragma unroll
      for (int d = 1; d < 16; d <<= 1) sum += __shfl_xor(sum, d);
      const float inv = 1.0f / sum;
#pragma unroll
      for (int ni = 0; ni < 4; ++ni)
        sP[i][ni * 16 + l15] = __float2bfloat16(s[ni] * inv);
    }
  }
  __syncthreads();

  f32x4 oacc[4][2];
#pragma unroll
  for (int mi = 0; mi < 4; ++mi)
#pragma unroll
    for (int ni = 0; ni < 2; ++ni) oacc[mi][ni] = (f32x4){0.f, 0.f, 0.f, 0.f};
#pragma unroll
  for (int kb = 0; kb < 2; ++kb) {
    bf16x8 ap[4], bv[2];
#pragma unroll
    for (int mi = 0; mi < 4; ++mi) ap[mi] = *(const bf16x8*)&sP[mi * 16 + l15][kb * 32 + l4 * 8];
#pragma unroll
    for (int ni = 0; ni < 2; ++ni) bv[ni] = *(const bf16x8*)&sVT[ni * 16 + l15][kb * 32 + l4 * 8];
#pragma unroll
    for (int mi = 0; mi < 4; ++mi)
#pragma unroll
      for (int ni = 0; ni < 2; ++ni)
        oacc[mi][ni] = __builtin_amdgcn_mfma_f32_16x16x32_bf16(ap[mi], bv[ni], oacc[mi][ni], 0, 0, 0);
  }

#pragma unroll
  for (int mi = 0; mi < 4; ++mi) {
#pragma unroll
    for (int rr = 0; rr < 4; ++rr) {
      const int i = mi * 16 + l4 * 4 + rr;
      if (i < 49) {
        const int r = i / 7, c = i - r * 7;
        const size_t grow = (size_t)b * 784 + (size_t)((wh * 7 + r) * 28 + wwc * 7 + c);
#pragma unroll
        for (int ni = 0; ni < 2; ++ni)
          o[grow * 576 + head * 32 + ni * 16 + l15] = __float2bfloat16(oacc[mi][ni][rr]);
      }
    }
  }
}

// ---------- depthwise 3x3 conv + folded BN, float4 over channels ----------
__global__ void conv_bn_kernel(const float* __restrict__ x1, const float* __restrict__ wT,
                               const float* __restrict__ st, float* __restrict__ x2) {
  const size_t total = (size_t)32 * 784 * 144;
  const size_t idx = (size_t)blockIdx.x * 256 + threadIdx.x;
  if (idx >= total) return;
  const int c4 = (int)(idx % 144);
  const size_t p = idx / 144;
  const int pix = (int)(p % 784);
  const int b = (int)(p / 784);
  const int i = pix / 28, j = pix - (pix / 28) * 28;
  const int c = c4 * 4;
  f32x4 acc = (f32x4){0.f, 0.f, 0.f, 0.f};
#pragma unroll
  for (int dh = -1; dh <= 1; ++dh) {
#pragma unroll
    for (int dw = -1; dw <= 1; ++dw) {
      const int ii = i + dh, jj = j + dw;
      if (ii >= 0 && ii < 28 && jj >= 0 && jj < 28) {
        const f32x4 v = *(const f32x4*)&x1[((size_t)b * 784 + ii * 28 + jj) * 576 + c];
        const f32x4 wv = *(const f32x4*)&wT[((dh + 1) * 3 + (dw + 1)) * 576 + c];
        acc += v * wv;
      }
    }
  }
  const f32x4 s = *(const f32x4*)&st[c];
  const f32x4 tt = *(const f32x4*)&st[576 + c];
  *(f32x4*)&x2[((size_t)b * 784 + pix) * 576 + c] = acc * s + tt;
}

// ---------- launch ----------
extern "C" void kernel_launch(void* const* d_in, const int* in_sizes, int n_in,
                              void* d_out, int out_size, void* d_ws, size_t ws_size,
                              hipStream_t stream) {
  (void)in_sizes; (void)n_in; (void)out_size; (void)ws_size;
  const float* x      = (const float*)d_in[0];
  const float* ln1g   = (const float*)d_in[1];
  const float* ln1b   = (const float*)d_in[2];
  const float* qkv_w  = (const float*)d_in[3];
  const float* qkv_b  = (const float*)d_in[4];
  const float* biases = (const float*)d_in[5];
  const float* proj_w = (const float*)d_in[6];
  const float* proj_b = (const float*)d_in[7];
  const float* conv_w = (const float*)d_in[8];
  const float* bng    = (const float*)d_in[9];
  const float* bnb    = (const float*)d_in[10];
  const float* bnm    = (const float*)d_in[11];
  const float* bnv    = (const float*)d_in[12];
  const float* ln2g   = (const float*)d_in[13];
  const float* ln2b   = (const float*)d_in[14];
  const float* fc1_w  = (const float*)d_in[15];
  const float* fc1_b  = (const float*)d_in[16];
  const float* fc2_w  = (const float*)d_in[17];
  const float* fc2_b  = (const float*)d_in[18];
  float* out = (float*)d_out;

  const int M = 25088;
  char* ws = (char*)d_ws;
  float* x2 = (float*)ws;
  char* regB = ws + 57802752;
  __hip_bfloat16* qkvb = (__hip_bfloat16*)regB;
  float*          x1   = (float*)regB;
  __hip_bfloat16* hm   = (__hip_bfloat16*)regB;
  char* regC = ws + 173408256;
  __hip_bfloat16* xn1  = (__hip_bfloat16*)regC;
  __hip_bfloat16* obuf = (__hip_bfloat16*)regC;
  __hip_bfloat16* xn2  = (__hip_bfloat16*)regC;
  char* regD = ws + 202309632;
  __hip_bfloat16* qkvT = (__hip_bfloat16*)regD;
  __hip_bfloat16* projT = (__hip_bfloat16*)(regD + 1990656);
  __hip_bfloat16* fc1T  = (__hip_bfloat16*)(regD + 1990656 + 663552);
  __hip_bfloat16* fc2T  = (__hip_bfloat16*)(regD + 1990656 + 663552 + 2654208);
  float* convT = (float*)(ws + 210272256);
  float* convST = convT + 9 * 576;

  // weight prep
  wt_kernel<<<dim3(1728 / 32, 576 / 32), 256, 0, stream>>>(qkv_w, qkvT, 576, 1728);
  wt_kernel<<<dim3(576 / 32, 576 / 32), 256, 0, stream>>>(proj_w, projT, 576, 576);
  wt_kernel<<<dim3(2304 / 32, 576 / 32), 256, 0, stream>>>(fc1_w, fc1T, 576, 2304);
  wt_kernel<<<dim3(576 / 32, 2304 / 32), 256, 0, stream>>>(fc2_w, fc2T, 2304, 576);
  convprep_kernel<<<(576 * 9 + 255) / 256, 256, 0, stream>>>(conv_w, bng, bnb, bnm, bnv, convT, convST);

  // 1. xn1 = LN1(x) bf16
  ln_bf16_kernel<<<M / 4, 256, 0, stream>>>(x, ln1g, ln1b, xn1);
  // 2. qkv = xn1 @ qkv_w + qkv_b (bf16 out); direct-global, grid 196 x 9
  gemm_direct<0, __hip_bfloat16><<<196 * 9, 256, 0, stream>>>(xn1, qkvT, qkv_b, nullptr, qkvb, M, 1728, 576);
  // 3. attention
  attn_mfma_kernel<<<512 * 18, 64, 0, stream>>>(qkvb, biases, obuf);
  // 4. x1 = x + (o @ proj_w + proj_b); staged control, grid 98 x 3
  gemm_bt<1, float><<<98 * 3, 512, 0, stream>>>(obuf, projT, proj_b, x, x1, M, 576, 576);
  // 5. x2 = BN(dwconv(x1))
  conv_bn_kernel<<<(32 * 784 * 144 + 255) / 256, 256, 0, stream>>>(x1, convT, convST, x2);
  // 6. xn2 = LN2(x2) bf16
  ln_bf16_kernel<<<M / 4, 256, 0, stream>>>(x2, ln2g, ln2b, xn2);
  // 7. hm = gelu(xn2 @ fc1_w + fc1_b) bf16; direct-global, grid 196 x 12
  gemm_direct<2, __hip_bfloat16><<<196 * 12, 256, 0, stream>>>(xn2, fc1T, fc1_b, nullptr, hm, M, 2304, 576);
  // 8. out = x2 + (hm @ fc2_w + fc2_b); direct-global, grid 196 x 3
  gemm_direct<1, float><<<196 * 3, 256, 0, stream>>>(hm, fc2T, fc2_b, x2, out, M, 576, 2304);
}

// Round 13
// 543.977 us; speedup vs baseline: 1.7091x; 1.7091x over previous
//
#include <hip/hip_runtime.h>
#include <hip/hip_bf16.h>

typedef __attribute__((ext_vector_type(8))) short bf16x8;
typedef __attribute__((ext_vector_type(4))) float f32x4;

static __device__ __forceinline__ void stf(float* p, size_t i, float v) { p[i] = v; }
static __device__ __forceinline__ void stf(__hip_bfloat16* p, size_t i, float v) { p[i] = __float2bfloat16(v); }

static __device__ __forceinline__ void gload_lds16(const void* g, void* l) {
  __builtin_amdgcn_global_load_lds((const __attribute__((address_space(1))) void*)g,
                                   (__attribute__((address_space(3))) void*)l, 16, 0, 0);
}

// ---------- weight transpose + bf16 convert: W[K][N] f32 -> WT[N][K] bf16 ----------
__global__ void wt_kernel(const float* __restrict__ W, __hip_bfloat16* __restrict__ WT, int K, int N) {
  __shared__ float tile[32][33];
  const int kb = blockIdx.y * 32, nb = blockIdx.x * 32;
  const int tx = threadIdx.x & 31, ty = threadIdx.x >> 5;
#pragma unroll
  for (int i = 0; i < 4; ++i)
    tile[ty + i * 8][tx] = W[(size_t)(kb + ty + i * 8) * N + nb + tx];
  __syncthreads();
#pragma unroll
  for (int i = 0; i < 4; ++i)
    WT[(size_t)(nb + ty + i * 8) * K + kb + tx] = __float2bfloat16(tile[tx][ty + i * 8]);
}

// ---------- conv prep ----------
__global__ void convprep_kernel(const float* __restrict__ w, const float* __restrict__ bng,
                                const float* __restrict__ bnb, const float* __restrict__ bnm,
                                const float* __restrict__ bnv, float* __restrict__ wT,
                                float* __restrict__ st) {
  const int i = blockIdx.x * 256 + threadIdx.x;
  if (i < 576 * 9) {
    const int t = i / 576, c = i - t * 576;
    wT[i] = w[c * 9 + t];
  }
  if (i < 576) {
    const float s = rsqrtf(bnv[i] + 1e-5f) * bng[i];
    st[i] = s;
    st[576 + i] = bnb[i] - bnm[i] * s;
  }
}

// ---------- fused LN -> bf16 ----------
__global__ void ln_bf16_kernel(const float* __restrict__ x, const float* __restrict__ g,
                               const float* __restrict__ b, __hip_bfloat16* __restrict__ y) {
  const int row = blockIdx.x * 4 + (threadIdx.x >> 6);
  const int lane = threadIdx.x & 63;
  const float* p = x + (size_t)row * 576;
  float vals[9];
  float s = 0.f, ss = 0.f;
#pragma unroll
  for (int i = 0; i < 9; ++i) {
    float v = p[lane + i * 64];
    vals[i] = v; s += v; ss += v * v;
  }
#pragma unroll
  for (int o = 32; o; o >>= 1) { s += __shfl_down(s, o); ss += __shfl_down(ss, o); }
  s = __shfl(s, 0); ss = __shfl(ss, 0);
  const float m = s * (1.f / 576.f);
  const float rstd = rsqrtf(ss * (1.f / 576.f) - m * m + 1e-5f);
  __hip_bfloat16* q = y + (size_t)row * 576;
#pragma unroll
  for (int i = 0; i < 9; ++i) {
    const int c = lane + i * 64;
    q[c] = __float2bfloat16((vals[i] - m) * rstd * g[c] + b[c]);
  }
}

// ---------- MFMA GEMM (R8 config — best measured): C = epi(A @ BT^T + bias) ----------
// tile BMxBN (128x192), BK=64, 4 waves (2x2), wave tile 64x96, gload_lds +
// XOR swizzle, XCD-bijective panel-major 1D grid, 2-phase __syncthreads loop.
// EPI: 0 none, 1 +res, 2 exact GELU
template <int BM, int BN, int EPI, typename TO>
__global__ __launch_bounds__(256, 2) void gemm_bt(
    const __hip_bfloat16* __restrict__ A, const __hip_bfloat16* __restrict__ BT,
    const float* __restrict__ bias, const float* __restrict__ res, TO* __restrict__ C,
    int M, int N, int K) {
  constexpr int WM = BM / 2, WN = BN / 2;
  constexpr int MI = WM / 16, NI = WN / 16;
  constexpr int AI = BM / 32, BI = BN / 32;
  __shared__ __hip_bfloat16 sA[2][BM * 64];
  __shared__ __hip_bfloat16 sB[2][BN * 64];
  const int t = threadIdx.x;
  const int lane = t & 63;
  const int w = t >> 6;
  const int nwg = gridDim.x;
  const int qq = nwg >> 3, r = nwg & 7;
  const int xcd = blockIdx.x & 7, lidx = blockIdx.x >> 3;
  const int wgid = (xcd < r ? xcd * (qq + 1) : r * (qq + 1) + (xcd - r) * qq) + lidx;
  const int nx = N / BN;
  const int bm = (wgid / nx) * BM, bn = (wgid % nx) * BN;
  const int wm = (w >> 1) * WM, wn = (w & 1) * WN;
  const int l15 = lane & 15, l4 = lane >> 4;

  f32x4 acc[MI][NI];
#pragma unroll
  for (int mi = 0; mi < MI; ++mi)
#pragma unroll
    for (int ni = 0; ni < NI; ++ni) acc[mi][ni] = (f32x4){0.f, 0.f, 0.f, 0.f};

  const int wave_base = t & ~63;

  auto stage = [&](int buf, int k0) {
#pragma unroll
    for (int i = 0; i < AI; ++i) {
      const int slot = i * 256 + t;
      const int row = slot >> 3, kst = slot & 7;
      const int ksrc = kst ^ (row & 7);
      const __hip_bfloat16* g = A + (size_t)(bm + row) * K + k0 + ksrc * 8;
      gload_lds16(g, sA[buf] + (i * 256 + wave_base) * 8);
    }
#pragma unroll
    for (int i = 0; i < BI; ++i) {
      const int slot = i * 256 + t;
      const int row = slot >> 3, kst = slot & 7;
      const int ksrc = kst ^ (row & 7);
      const __hip_bfloat16* g = BT + (size_t)(bn + row) * K + k0 + ksrc * 8;
      gload_lds16(g, sB[buf] + (i * 256 + wave_base) * 8);
    }
  };

  auto compute = [&](int buf) {
    const __hip_bfloat16* pA = sA[buf];
    const __hip_bfloat16* pB = sB[buf];
#pragma unroll
    for (int kb = 0; kb < 2; ++kb) {
      bf16x8 a[MI], b[NI];
      const int kblk = kb * 4 + l4;
#pragma unroll
      for (int mi = 0; mi < MI; ++mi) {
        const int row = wm + mi * 16 + l15;
        a[mi] = *(const bf16x8*)(pA + row * 64 + ((kblk ^ (row & 7)) * 8));
      }
#pragma unroll
      for (int ni = 0; ni < NI; ++ni) {
        const int row = wn + ni * 16 + l15;
        b[ni] = *(const bf16x8*)(pB + row * 64 + ((kblk ^ (row & 7)) * 8));
      }
#pragma unroll
      for (int mi = 0; mi < MI; ++mi)
#pragma unroll
        for (int ni = 0; ni < NI; ++ni)
          acc[mi][ni] = __builtin_amdgcn_mfma_f32_16x16x32_bf16(a[mi], b[ni], acc[mi][ni], 0, 0, 0);
    }
  };

  const int nt = K >> 6;
  stage(0, 0);
  __syncthreads();
  int cur = 0;
  for (int tt = 0; tt < nt - 1; ++tt) {
    stage(cur ^ 1, (tt + 1) << 6);
    compute(cur);
    __syncthreads();
    cur ^= 1;
  }
  compute(cur);

#pragma unroll
  for (int mi = 0; mi < MI; ++mi) {
    const int mrow = bm + wm + mi * 16 + l4 * 4;
#pragma unroll
    for (int ni = 0; ni < NI; ++ni) {
      const int col = bn + wn + ni * 16 + l15;
      const float bv = bias[col];
#pragma unroll
      for (int r2 = 0; r2 < 4; ++r2) {
        const size_t idx = (size_t)(mrow + r2) * N + col;
        float v = acc[mi][ni][r2] + bv;
        if (EPI == 1) v += res[idx];
        if (EPI == 2) v = 0.5f * v * (1.0f + erff(v * 0.70710678118654752f));
        stf(C, idx, v);
      }
    }
  }
}

// ---------- MFMA windowed attention, low-LDS: Q/K fragments direct from global ----------
// 1 wave per (window, head). LDS = V^T (4.6KB) + P (9.2KB) ~= 13.8KB/wave
// (was 28.6KB) -> ~2x occupancy. Q/K frag loads hit L1/L2 (qkv rows hot).
// Pad tokens (>=49) clamp to token 0: S cols masked to -1e30, S rows discarded.
__global__ __launch_bounds__(64) void attn_mfma_kernel(
    const __hip_bfloat16* __restrict__ qkv, const float* __restrict__ biases,
    __hip_bfloat16* __restrict__ o) {
  __shared__ __hip_bfloat16 sVT[32][72];
  __shared__ __hip_bfloat16 sP[64][72];

  const int wid  = blockIdx.x / 18;
  const int head = blockIdx.x - wid * 18;
  const int b  = wid >> 4;
  const int wi = wid & 15;
  const int wh = wi >> 2, wwc = wi & 3;
  const int lane = threadIdx.x;
  const int l15 = lane & 15, l4 = lane >> 4;

  auto growof = [&](int tkn) -> size_t {
    const int r = tkn / 7, c = tkn - r * 7;
    return (size_t)b * 784 + (size_t)((wh * 7 + r) * 28 + wwc * 7 + c);
  };

  // stage V^T (transposed scatter)
  for (int idx = lane; idx < 49 * 4; idx += 64) {
    const int tkn = idx >> 2, part = idx & 3;
    const bf16x8 v = *(const bf16x8*)(qkv + growof(tkn) * 1728 + head * 96 + 64 + part * 8);
    const short* sv = (const short*)&v;
#pragma unroll
    for (int e = 0; e < 8; ++e)
      sVT[part * 8 + e][tkn] = *(const __hip_bfloat16*)&sv[e];
  }
  for (int idx = lane; idx < 32 * 15; idx += 64) {
    const int d = idx / 15, tt = 49 + (idx - d * 15);
    sVT[d][tt] = __float2bfloat16(0.0f);
  }

  // Q/K fragments direct from global
  bf16x8 aq[4], bk[4];
#pragma unroll
  for (int mi = 0; mi < 4; ++mi) {
    int tk = mi * 16 + l15; if (tk > 48) tk = 0;
    aq[mi] = *(const bf16x8*)(qkv + growof(tk) * 1728 + head * 96 + l4 * 8);
  }
#pragma unroll
  for (int ni = 0; ni < 4; ++ni) {
    int tk = ni * 16 + l15; if (tk > 48) tk = 0;
    bk[ni] = *(const bf16x8*)(qkv + growof(tk) * 1728 + head * 96 + 32 + l4 * 8);
  }

  // S = Q @ K^T (64x64 padded)
  f32x4 acc[4][4];
#pragma unroll
  for (int mi = 0; mi < 4; ++mi)
#pragma unroll
    for (int ni = 0; ni < 4; ++ni) acc[mi][ni] = (f32x4){0.f, 0.f, 0.f, 0.f};
#pragma unroll
  for (int mi = 0; mi < 4; ++mi)
#pragma unroll
    for (int ni = 0; ni < 4; ++ni)
      acc[mi][ni] = __builtin_amdgcn_mfma_f32_16x16x32_bf16(aq[mi], bk[ni], acc[mi][ni], 0, 0, 0);

  // bias + masked wave-parallel softmax -> P (bf16 LDS)
  const float scale = 0.17677669529663687f;
  const float* btab = biases + head * 49;
#pragma unroll
  for (int mi = 0; mi < 4; ++mi) {
#pragma unroll
    for (int rr = 0; rr < 4; ++rr) {
      const int i = mi * 16 + l4 * 4 + rr;
      const int ic = i < 49 ? i : 0;
      const int ri = ic / 7, ci = ic - ri * 7;
      float s[4];
#pragma unroll
      for (int ni = 0; ni < 4; ++ni) {
        const int j = ni * 16 + l15;
        if (j < 49) {
          const int rj = j / 7, cj = j - rj * 7;
          s[ni] = acc[mi][ni][rr] * scale + btab[__builtin_abs(ri - rj) * 7 + __builtin_abs(ci - cj)];
        } else {
          s[ni] = -1e30f;
        }
      }
      float m = fmaxf(fmaxf(s[0], s[1]), fmaxf(s[2], s[3]));
#pragma unroll
      for (int d = 1; d < 16; d <<= 1) m = fmaxf(m, __shfl_xor(m, d));
      float sum = 0.f;
#pragma unroll
      for (int ni = 0; ni < 4; ++ni) { s[ni] = __expf(s[ni] - m); sum += s[ni]; }
#pragma unroll
      for (int d = 1; d < 16; d <<= 1) sum += __shfl_xor(sum, d);
      const float inv = 1.0f / sum;
#pragma unroll
      for (int ni = 0; ni < 4; ++ni)
        sP[i][ni * 16 + l15] = __float2bfloat16(s[ni] * inv);
    }
  }
  __syncthreads();  // V^T + P writes visible

  // O = P @ V
  f32x4 oacc[4][2];
#pragma unroll
  for (int mi = 0; mi < 4; ++mi)
#pragma unroll
    for (int ni = 0; ni < 2; ++ni) oacc[mi][ni] = (f32x4){0.f, 0.f, 0.f, 0.f};
#pragma unroll
  for (int kb = 0; kb < 2; ++kb) {
    bf16x8 ap[4], bv[2];
#pragma unroll
    for (int mi = 0; mi < 4; ++mi) ap[mi] = *(const bf16x8*)&sP[mi * 16 + l15][kb * 32 + l4 * 8];
#pragma unroll
    for (int ni = 0; ni < 2; ++ni) bv[ni] = *(const bf16x8*)&sVT[ni * 16 + l15][kb * 32 + l4 * 8];
#pragma unroll
    for (int mi = 0; mi < 4; ++mi)
#pragma unroll
      for (int ni = 0; ni < 2; ++ni)
        oacc[mi][ni] = __builtin_amdgcn_mfma_f32_16x16x32_bf16(ap[mi], bv[ni], oacc[mi][ni], 0, 0, 0);
  }

#pragma unroll
  for (int mi = 0; mi < 4; ++mi) {
#pragma unroll
    for (int rr = 0; rr < 4; ++rr) {
      const int i = mi * 16 + l4 * 4 + rr;
      if (i < 49) {
        const size_t grow = growof(i);
#pragma unroll
        for (int ni = 0; ni < 2; ++ni)
          o[grow * 576 + head * 32 + ni * 16 + l15] = __float2bfloat16(oacc[mi][ni][rr]);
      }
    }
  }
}

// ---------- depthwise 3x3 conv + folded BN, float4 over channels ----------
__global__ void conv_bn_kernel(const float* __restrict__ x1, const float* __restrict__ wT,
                               const float* __restrict__ st, float* __restrict__ x2) {
  const size_t total = (size_t)32 * 784 * 144;
  const size_t idx = (size_t)blockIdx.x * 256 + threadIdx.x;
  if (idx >= total) return;
  const int c4 = (int)(idx % 144);
  const size_t p = idx / 144;
  const int pix = (int)(p % 784);
  const int b = (int)(p / 784);
  const int i = pix / 28, j = pix - (pix / 28) * 28;
  const int c = c4 * 4;
  f32x4 acc = (f32x4){0.f, 0.f, 0.f, 0.f};
#pragma unroll
  for (int dh = -1; dh <= 1; ++dh) {
#pragma unroll
    for (int dw = -1; dw <= 1; ++dw) {
      const int ii = i + dh, jj = j + dw;
      if (ii >= 0 && ii < 28 && jj >= 0 && jj < 28) {
        const f32x4 v = *(const f32x4*)&x1[((size_t)b * 784 + ii * 28 + jj) * 576 + c];
        const f32x4 wv = *(const f32x4*)&wT[((dh + 1) * 3 + (dw + 1)) * 576 + c];
        acc += v * wv;
      }
    }
  }
  const f32x4 s = *(const f32x4*)&st[c];
  const f32x4 tt = *(const f32x4*)&st[576 + c];
  *(f32x4*)&x2[((size_t)b * 784 + pix) * 576 + c] = acc * s + tt;
}

// ---------- launch ----------
extern "C" void kernel_launch(void* const* d_in, const int* in_sizes, int n_in,
                              void* d_out, int out_size, void* d_ws, size_t ws_size,
                              hipStream_t stream) {
  (void)in_sizes; (void)n_in; (void)out_size; (void)ws_size;
  const float* x      = (const float*)d_in[0];
  const float* ln1g   = (const float*)d_in[1];
  const float* ln1b   = (const float*)d_in[2];
  const float* qkv_w  = (const float*)d_in[3];
  const float* qkv_b  = (const float*)d_in[4];
  const float* biases = (const float*)d_in[5];
  const float* proj_w = (const float*)d_in[6];
  const float* proj_b = (const float*)d_in[7];
  const float* conv_w = (const float*)d_in[8];
  const float* bng    = (const float*)d_in[9];
  const float* bnb    = (const float*)d_in[10];
  const float* bnm    = (const float*)d_in[11];
  const float* bnv    = (const float*)d_in[12];
  const float* ln2g   = (const float*)d_in[13];
  const float* ln2b   = (const float*)d_in[14];
  const float* fc1_w  = (const float*)d_in[15];
  const float* fc1_b  = (const float*)d_in[16];
  const float* fc2_w  = (const float*)d_in[17];
  const float* fc2_b  = (const float*)d_in[18];
  float* out = (float*)d_out;

  const int M = 25088;
  char* ws = (char*)d_ws;
  float* x2 = (float*)ws;
  char* regB = ws + 57802752;
  __hip_bfloat16* qkvb = (__hip_bfloat16*)regB;
  float*          x1   = (float*)regB;
  __hip_bfloat16* hm   = (__hip_bfloat16*)regB;
  char* regC = ws + 173408256;
  __hip_bfloat16* xn1  = (__hip_bfloat16*)regC;
  __hip_bfloat16* obuf = (__hip_bfloat16*)regC;
  __hip_bfloat16* xn2  = (__hip_bfloat16*)regC;
  char* regD = ws + 202309632;
  __hip_bfloat16* qkvT = (__hip_bfloat16*)regD;
  __hip_bfloat16* projT = (__hip_bfloat16*)(regD + 1990656);
  __hip_bfloat16* fc1T  = (__hip_bfloat16*)(regD + 1990656 + 663552);
  __hip_bfloat16* fc2T  = (__hip_bfloat16*)(regD + 1990656 + 663552 + 2654208);
  float* convT = (float*)(ws + 210272256);
  float* convST = convT + 9 * 576;

  // weight prep
  wt_kernel<<<dim3(1728 / 32, 576 / 32), 256, 0, stream>>>(qkv_w, qkvT, 576, 1728);
  wt_kernel<<<dim3(576 / 32, 576 / 32), 256, 0, stream>>>(proj_w, projT, 576, 576);
  wt_kernel<<<dim3(2304 / 32, 576 / 32), 256, 0, stream>>>(fc1_w, fc1T, 576, 2304);
  wt_kernel<<<dim3(576 / 32, 2304 / 32), 256, 0, stream>>>(fc2_w, fc2T, 2304, 576);
  convprep_kernel<<<(576 * 9 + 255) / 256, 256, 0, stream>>>(conv_w, bng, bnb, bnm, bnv, convT, convST);

  // 1. xn1 = LN1(x) bf16
  ln_bf16_kernel<<<M / 4, 256, 0, stream>>>(x, ln1g, ln1b, xn1);
  // 2. qkv = xn1 @ qkv_w + qkv_b (bf16 out)
  gemm_bt<128, 192, 0, __hip_bfloat16><<<9 * 196, 256, 0, stream>>>(xn1, qkvT, qkv_b, nullptr, qkvb, M, 1728, 576);
  // 3. attention (low-LDS MFMA)
  attn_mfma_kernel<<<512 * 18, 64, 0, stream>>>(qkvb, biases, obuf);
  // 4. x1 = x + (o @ proj_w + proj_b)
  gemm_bt<128, 192, 1, float><<<3 * 196, 256, 0, stream>>>(obuf, projT, proj_b, x, x1, M, 576, 576);
  // 5. x2 = BN(dwconv(x1))
  conv_bn_kernel<<<(32 * 784 * 144 + 255) / 256, 256, 0, stream>>>(x1, convT, convST, x2);
  // 6. xn2 = LN2(x2) bf16
  ln_bf16_kernel<<<M / 4, 256, 0, stream>>>(x2, ln2g, ln2b, xn2);
  // 7. hm = gelu(xn2 @ fc1_w + fc1_b) bf16
  gemm_bt<128, 192, 2, __hip_bfloat16><<<12 * 196, 256, 0, stream>>>(xn2, fc1T, fc1_b, nullptr, hm, M, 2304, 576);
  // 8. out = x2 + (hm @ fc2_w + fc2_b)
  gemm_bt<128, 192, 1, float><<<3 * 196, 256, 0, stream>>>(hm, fc2T, fc2_b, x2, out, M, 576, 2304);
}

// Round 14
// 516.552 us; speedup vs baseline: 1.7999x; 1.0531x over previous
//
#include <hip/hip_runtime.h>
#include <hip/hip_bf16.h>

typedef __attribute__((ext_vector_type(8))) short bf16x8;
typedef __attribute__((ext_vector_type(4))) float f32x4;

static __device__ __forceinline__ void stf(float* p, size_t i, float v) { p[i] = v; }
static __device__ __forceinline__ void stf(__hip_bfloat16* p, size_t i, float v) { p[i] = __float2bfloat16(v); }

static __device__ __forceinline__ void gload_lds16(const void* g, void* l) {
  __builtin_amdgcn_global_load_lds((const __attribute__((address_space(1))) void*)g,
                                   (__attribute__((address_space(3))) void*)l, 16, 0, 0);
}

// ---------- weight transpose + bf16 convert: W[K][N] f32 -> WT[N][K] bf16 ----------
__global__ void wt_kernel(const float* __restrict__ W, __hip_bfloat16* __restrict__ WT, int K, int N) {
  __shared__ float tile[32][33];
  const int kb = blockIdx.y * 32, nb = blockIdx.x * 32;
  const int tx = threadIdx.x & 31, ty = threadIdx.x >> 5;
#pragma unroll
  for (int i = 0; i < 4; ++i)
    tile[ty + i * 8][tx] = W[(size_t)(kb + ty + i * 8) * N + nb + tx];
  __syncthreads();
#pragma unroll
  for (int i = 0; i < 4; ++i)
    WT[(size_t)(nb + ty + i * 8) * K + kb + tx] = __float2bfloat16(tile[tx][ty + i * 8]);
}

// ---------- conv prep ----------
__global__ void convprep_kernel(const float* __restrict__ w, const float* __restrict__ bng,
                                const float* __restrict__ bnb, const float* __restrict__ bnm,
                                const float* __restrict__ bnv, float* __restrict__ wT,
                                float* __restrict__ st) {
  const int i = blockIdx.x * 256 + threadIdx.x;
  if (i < 576 * 9) {
    const int t = i / 576, c = i - t * 576;
    wT[i] = w[c * 9 + t];
  }
  if (i < 576) {
    const float s = rsqrtf(bnv[i] + 1e-5f) * bng[i];
    st[i] = s;
    st[576 + i] = bnb[i] - bnm[i] * s;
  }
}

// ---------- fused LN -> bf16 ----------
__global__ void ln_bf16_kernel(const float* __restrict__ x, const float* __restrict__ g,
                               const float* __restrict__ b, __hip_bfloat16* __restrict__ y) {
  const int row = blockIdx.x * 4 + (threadIdx.x >> 6);
  const int lane = threadIdx.x & 63;
  const float* p = x + (size_t)row * 576;
  float vals[9];
  float s = 0.f, ss = 0.f;
#pragma unroll
  for (int i = 0; i < 9; ++i) {
    float v = p[lane + i * 64];
    vals[i] = v; s += v; ss += v * v;
  }
#pragma unroll
  for (int o = 32; o; o >>= 1) { s += __shfl_down(s, o); ss += __shfl_down(ss, o); }
  s = __shfl(s, 0); ss = __shfl(ss, 0);
  const float m = s * (1.f / 576.f);
  const float rstd = rsqrtf(ss * (1.f / 576.f) - m * m + 1e-5f);
  __hip_bfloat16* q = y + (size_t)row * 576;
#pragma unroll
  for (int i = 0; i < 9; ++i) {
    const int c = lane + i * 64;
    q[c] = __float2bfloat16((vals[i] - m) * rstd * g[c] + b[c]);
  }
}

// ---------- MFMA GEMM, high-occupancy: 128x64 tile, BK=32, 24KB LDS ----------
// 6 blocks/CU (24 waves/CU): barrier-gang stalls of one block overlap with
// compute of 5 others -- the only monotone correlate of GEMM speed across
// R6-R12 variants was blocks/CU (R6 3blk=172us beat all 1-2blk configs).
// 4 waves (2x2), wave tile 64x32 (MI=4,NI=2), 8 MFMA/K-step, XOR swizzle
// (chunk ^= row&3), ascending-K accumulation (bit-identical to prior rounds).
// EPI: 0 none, 1 +res, 2 exact GELU
template <int EPI, typename TO>
__global__ __launch_bounds__(256, 6) void gemm_bt(
    const __hip_bfloat16* __restrict__ A, const __hip_bfloat16* __restrict__ BT,
    const float* __restrict__ bias, const float* __restrict__ res, TO* __restrict__ C,
    int M, int N, int K) {
  __shared__ __hip_bfloat16 sA[2][128 * 32];
  __shared__ __hip_bfloat16 sB[2][64 * 32];
  const int t = threadIdx.x;
  const int lane = t & 63;
  const int w = t >> 6;
  const int nwg = gridDim.x;
  const int qq = nwg >> 3, r = nwg & 7;
  const int xcd = blockIdx.x & 7, lidx = blockIdx.x >> 3;
  const int wgid = (xcd < r ? xcd * (qq + 1) : r * (qq + 1) + (xcd - r) * qq) + lidx;
  const int nx = N >> 6;
  const int bm = (wgid / nx) * 128, bn = (wgid % nx) * 64;
  const int wm = (w >> 1) * 64, wn = (w & 1) * 32;
  const int l15 = lane & 15, l4 = lane >> 4;
  const int wave_base = t & ~63;

  f32x4 acc[4][2];
#pragma unroll
  for (int mi = 0; mi < 4; ++mi)
#pragma unroll
    for (int ni = 0; ni < 2; ++ni) acc[mi][ni] = (f32x4){0.f, 0.f, 0.f, 0.f};

  auto stage = [&](int buf, int k0) {
    // A tile 128x32: 512 chunks of 8 bf16; 2 iters. row=slot>>2, kst=slot&3.
#pragma unroll
    for (int i = 0; i < 2; ++i) {
      const int slot = i * 256 + t;
      const int row = slot >> 2, kst = slot & 3;
      const int ksrc = kst ^ (row & 3);
      gload_lds16(A + (size_t)(bm + row) * K + k0 + ksrc * 8,
                  sA[buf] + (i * 256 + wave_base) * 8);
    }
    // B tile 64x32: 256 chunks; 1 iter.
    {
      const int row = t >> 2, kst = t & 3;
      const int ksrc = kst ^ (row & 3);
      gload_lds16(BT + (size_t)(bn + row) * K + k0 + ksrc * 8,
                  sB[buf] + wave_base * 8);
    }
  };

  auto compute = [&](int buf) {
    bf16x8 a[4], b[2];
#pragma unroll
    for (int mi = 0; mi < 4; ++mi) {
      const int row = wm + mi * 16 + l15;
      a[mi] = *(const bf16x8*)(&sA[buf][row * 32 + ((l4 ^ (row & 3)) * 8)]);
    }
#pragma unroll
    for (int ni = 0; ni < 2; ++ni) {
      const int row = wn + ni * 16 + l15;
      b[ni] = *(const bf16x8*)(&sB[buf][row * 32 + ((l4 ^ (row & 3)) * 8)]);
    }
#pragma unroll
    for (int mi = 0; mi < 4; ++mi)
#pragma unroll
      for (int ni = 0; ni < 2; ++ni)
        acc[mi][ni] = __builtin_amdgcn_mfma_f32_16x16x32_bf16(a[mi], b[ni], acc[mi][ni], 0, 0, 0);
  };

  const int nt = K >> 5;
  stage(0, 0);
  __syncthreads();
  int cur = 0;
  for (int tt = 0; tt < nt - 1; ++tt) {
    stage(cur ^ 1, (tt + 1) << 5);
    compute(cur);
    __syncthreads();
    cur ^= 1;
  }
  compute(cur);

#pragma unroll
  for (int mi = 0; mi < 4; ++mi) {
    const int mrow = bm + wm + mi * 16 + l4 * 4;
#pragma unroll
    for (int ni = 0; ni < 2; ++ni) {
      const int col = bn + wn + ni * 16 + l15;
      const float bv = bias[col];
#pragma unroll
      for (int r2 = 0; r2 < 4; ++r2) {
        const size_t idx = (size_t)(mrow + r2) * N + col;
        float v = acc[mi][ni][r2] + bv;
        if (EPI == 1) v += res[idx];
        if (EPI == 2) v = 0.5f * v * (1.0f + erff(v * 0.70710678118654752f));
        stf(C, idx, v);
      }
    }
  }
}

// ---------- MFMA windowed attention, low-LDS (R12 config, kept) ----------
__global__ __launch_bounds__(64) void attn_mfma_kernel(
    const __hip_bfloat16* __restrict__ qkv, const float* __restrict__ biases,
    __hip_bfloat16* __restrict__ o) {
  __shared__ __hip_bfloat16 sVT[32][72];
  __shared__ __hip_bfloat16 sP[64][72];

  const int wid  = blockIdx.x / 18;
  const int head = blockIdx.x - wid * 18;
  const int b  = wid >> 4;
  const int wi = wid & 15;
  const int wh = wi >> 2, wwc = wi & 3;
  const int lane = threadIdx.x;
  const int l15 = lane & 15, l4 = lane >> 4;

  auto growof = [&](int tkn) -> size_t {
    const int r = tkn / 7, c = tkn - r * 7;
    return (size_t)b * 784 + (size_t)((wh * 7 + r) * 28 + wwc * 7 + c);
  };

  for (int idx = lane; idx < 49 * 4; idx += 64) {
    const int tkn = idx >> 2, part = idx & 3;
    const bf16x8 v = *(const bf16x8*)(qkv + growof(tkn) * 1728 + head * 96 + 64 + part * 8);
    const short* sv = (const short*)&v;
#pragma unroll
    for (int e = 0; e < 8; ++e)
      sVT[part * 8 + e][tkn] = *(const __hip_bfloat16*)&sv[e];
  }
  for (int idx = lane; idx < 32 * 15; idx += 64) {
    const int d = idx / 15, tt = 49 + (idx - d * 15);
    sVT[d][tt] = __float2bfloat16(0.0f);
  }

  bf16x8 aq[4], bk[4];
#pragma unroll
  for (int mi = 0; mi < 4; ++mi) {
    int tk = mi * 16 + l15; if (tk > 48) tk = 0;
    aq[mi] = *(const bf16x8*)(qkv + growof(tk) * 1728 + head * 96 + l4 * 8);
  }
#pragma unroll
  for (int ni = 0; ni < 4; ++ni) {
    int tk = ni * 16 + l15; if (tk > 48) tk = 0;
    bk[ni] = *(const bf16x8*)(qkv + growof(tk) * 1728 + head * 96 + 32 + l4 * 8);
  }

  f32x4 acc[4][4];
#pragma unroll
  for (int mi = 0; mi < 4; ++mi)
#pragma unroll
    for (int ni = 0; ni < 4; ++ni) acc[mi][ni] = (f32x4){0.f, 0.f, 0.f, 0.f};
#pragma unroll
  for (int mi = 0; mi < 4; ++mi)
#pragma unroll
    for (int ni = 0; ni < 4; ++ni)
      acc[mi][ni] = __builtin_amdgcn_mfma_f32_16x16x32_bf16(aq[mi], bk[ni], acc[mi][ni], 0, 0, 0);

  const float scale = 0.17677669529663687f;
  const float* btab = biases + head * 49;
#pragma unroll
  for (int mi = 0; mi < 4; ++mi) {
#pragma unroll
    for (int rr = 0; rr < 4; ++rr) {
      const int i = mi * 16 + l4 * 4 + rr;
      const int ic = i < 49 ? i : 0;
      const int ri = ic / 7, ci = ic - ri * 7;
      float s[4];
#pragma unroll
      for (int ni = 0; ni < 4; ++ni) {
        const int j = ni * 16 + l15;
        if (j < 49) {
          const int rj = j / 7, cj = j - rj * 7;
          s[ni] = acc[mi][ni][rr] * scale + btab[__builtin_abs(ri - rj) * 7 + __builtin_abs(ci - cj)];
        } else {
          s[ni] = -1e30f;
        }
      }
      float m = fmaxf(fmaxf(s[0], s[1]), fmaxf(s[2], s[3]));
#pragma unroll
      for (int d = 1; d < 16; d <<= 1) m = fmaxf(m, __shfl_xor(m, d));
      float sum = 0.f;
#pragma unroll
      for (int ni = 0; ni < 4; ++ni) { s[ni] = __expf(s[ni] - m); sum += s[ni]; }
#pragma unroll
      for (int d = 1; d < 16; d <<= 1) sum += __shfl_xor(sum, d);
      const float inv = 1.0f / sum;
#pragma unroll
      for (int ni = 0; ni < 4; ++ni)
        sP[i][ni * 16 + l15] = __float2bfloat16(s[ni] * inv);
    }
  }
  __syncthreads();

  f32x4 oacc[4][2];
#pragma unroll
  for (int mi = 0; mi < 4; ++mi)
#pragma unroll
    for (int ni = 0; ni < 2; ++ni) oacc[mi][ni] = (f32x4){0.f, 0.f, 0.f, 0.f};
#pragma unroll
  for (int kb = 0; kb < 2; ++kb) {
    bf16x8 ap[4], bv[2];
#pragma unroll
    for (int mi = 0; mi < 4; ++mi) ap[mi] = *(const bf16x8*)&sP[mi * 16 + l15][kb * 32 + l4 * 8];
#pragma unroll
    for (int ni = 0; ni < 2; ++ni) bv[ni] = *(const bf16x8*)&sVT[ni * 16 + l15][kb * 32 + l4 * 8];
#pragma unroll
    for (int mi = 0; mi < 4; ++mi)
#pragma unroll
      for (int ni = 0; ni < 2; ++ni)
        oacc[mi][ni] = __builtin_amdgcn_mfma_f32_16x16x32_bf16(ap[mi], bv[ni], oacc[mi][ni], 0, 0, 0);
  }

#pragma unroll
  for (int mi = 0; mi < 4; ++mi) {
#pragma unroll
    for (int rr = 0; rr < 4; ++rr) {
      const int i = mi * 16 + l4 * 4 + rr;
      if (i < 49) {
        const size_t grow = growof(i);
#pragma unroll
        for (int ni = 0; ni < 2; ++ni)
          o[grow * 576 + head * 32 + ni * 16 + l15] = __float2bfloat16(oacc[mi][ni][rr]);
      }
    }
  }
}

// ---------- depthwise 3x3 conv + folded BN, float4 over channels ----------
__global__ void conv_bn_kernel(const float* __restrict__ x1, const float* __restrict__ wT,
                               const float* __restrict__ st, float* __restrict__ x2) {
  const size_t total = (size_t)32 * 784 * 144;
  const size_t idx = (size_t)blockIdx.x * 256 + threadIdx.x;
  if (idx >= total) return;
  const int c4 = (int)(idx % 144);
  const size_t p = idx / 144;
  const int pix = (int)(p % 784);
  const int b = (int)(p / 784);
  const int i = pix / 28, j = pix - (pix / 28) * 28;
  const int c = c4 * 4;
  f32x4 acc = (f32x4){0.f, 0.f, 0.f, 0.f};
#pragma unroll
  for (int dh = -1; dh <= 1; ++dh) {
#pragma unroll
    for (int dw = -1; dw <= 1; ++dw) {
      const int ii = i + dh, jj = j + dw;
      if (ii >= 0 && ii < 28 && jj >= 0 && jj < 28) {
        const f32x4 v = *(const f32x4*)&x1[((size_t)b * 784 + ii * 28 + jj) * 576 + c];
        const f32x4 wv = *(const f32x4*)&wT[((dh + 1) * 3 + (dw + 1)) * 576 + c];
        acc += v * wv;
      }
    }
  }
  const f32x4 s = *(const f32x4*)&st[c];
  const f32x4 tt = *(const f32x4*)&st[576 + c];
  *(f32x4*)&x2[((size_t)b * 784 + pix) * 576 + c] = acc * s + tt;
}

// ---------- launch ----------
extern "C" void kernel_launch(void* const* d_in, const int* in_sizes, int n_in,
                              void* d_out, int out_size, void* d_ws, size_t ws_size,
                              hipStream_t stream) {
  (void)in_sizes; (void)n_in; (void)out_size; (void)ws_size;
  const float* x      = (const float*)d_in[0];
  const float* ln1g   = (const float*)d_in[1];
  const float* ln1b   = (const float*)d_in[2];
  const float* qkv_w  = (const float*)d_in[3];
  const float* qkv_b  = (const float*)d_in[4];
  const float* biases = (const float*)d_in[5];
  const float* proj_w = (const float*)d_in[6];
  const float* proj_b = (const float*)d_in[7];
  const float* conv_w = (const float*)d_in[8];
  const float* bng    = (const float*)d_in[9];
  const float* bnb    = (const float*)d_in[10];
  const float* bnm    = (const float*)d_in[11];
  const float* bnv    = (const float*)d_in[12];
  const float* ln2g   = (const float*)d_in[13];
  const float* ln2b   = (const float*)d_in[14];
  const float* fc1_w  = (const float*)d_in[15];
  const float* fc1_b  = (const float*)d_in[16];
  const float* fc2_w  = (const float*)d_in[17];
  const float* fc2_b  = (const float*)d_in[18];
  float* out = (float*)d_out;

  const int M = 25088;
  char* ws = (char*)d_ws;
  float* x2 = (float*)ws;
  char* regB = ws + 57802752;
  __hip_bfloat16* qkvb = (__hip_bfloat16*)regB;
  float*          x1   = (float*)regB;
  __hip_bfloat16* hm   = (__hip_bfloat16*)regB;
  char* regC = ws + 173408256;
  __hip_bfloat16* xn1  = (__hip_bfloat16*)regC;
  __hip_bfloat16* obuf = (__hip_bfloat16*)regC;
  __hip_bfloat16* xn2  = (__hip_bfloat16*)regC;
  char* regD = ws + 202309632;
  __hip_bfloat16* qkvT = (__hip_bfloat16*)regD;
  __hip_bfloat16* projT = (__hip_bfloat16*)(regD + 1990656);
  __hip_bfloat16* fc1T  = (__hip_bfloat16*)(regD + 1990656 + 663552);
  __hip_bfloat16* fc2T  = (__hip_bfloat16*)(regD + 1990656 + 663552 + 2654208);
  float* convT = (float*)(ws + 210272256);
  float* convST = convT + 9 * 576;

  // weight prep
  wt_kernel<<<dim3(1728 / 32, 576 / 32), 256, 0, stream>>>(qkv_w, qkvT, 576, 1728);
  wt_kernel<<<dim3(576 / 32, 576 / 32), 256, 0, stream>>>(proj_w, projT, 576, 576);
  wt_kernel<<<dim3(2304 / 32, 576 / 32), 256, 0, stream>>>(fc1_w, fc1T, 576, 2304);
  wt_kernel<<<dim3(576 / 32, 2304 / 32), 256, 0, stream>>>(fc2_w, fc2T, 2304, 576);
  convprep_kernel<<<(576 * 9 + 255) / 256, 256, 0, stream>>>(conv_w, bng, bnb, bnm, bnv, convT, convST);

  // 1. xn1 = LN1(x) bf16
  ln_bf16_kernel<<<M / 4, 256, 0, stream>>>(x, ln1g, ln1b, xn1);
  // 2. qkv = xn1 @ qkv_w + qkv_b (bf16 out); grid 196 x 27
  gemm_bt<0, __hip_bfloat16><<<196 * 27, 256, 0, stream>>>(xn1, qkvT, qkv_b, nullptr, qkvb, M, 1728, 576);
  // 3. attention (low-LDS MFMA)
  attn_mfma_kernel<<<512 * 18, 64, 0, stream>>>(qkvb, biases, obuf);
  // 4. x1 = x + (o @ proj_w + proj_b); grid 196 x 9
  gemm_bt<1, float><<<196 * 9, 256, 0, stream>>>(obuf, projT, proj_b, x, x1, M, 576, 576);
  // 5. x2 = BN(dwconv(x1))
  conv_bn_kernel<<<(32 * 784 * 144 + 255) / 256, 256, 0, stream>>>(x1, convT, convST, x2);
  // 6. xn2 = LN2(x2) bf16
  ln_bf16_kernel<<<M / 4, 256, 0, stream>>>(x2, ln2g, ln2b, xn2);
  // 7. hm = gelu(xn2 @ fc1_w + fc1_b) bf16; grid 196 x 36
  gemm_bt<2, __hip_bfloat16><<<196 * 36, 256, 0, stream>>>(xn2, fc1T, fc1_b, nullptr, hm, M, 2304, 576);
  // 8. out = x2 + (hm @ fc2_w + fc2_b); grid 196 x 9
  gemm_bt<1, float><<<196 * 9, 256, 0, stream>>>(hm, fc2T, fc2_b, x2, out, M, 576, 2304);
}

// Round 16
// 513.950 us; speedup vs baseline: 1.8090x; 1.0051x over previous
//
#include <hip/hip_runtime.h>
#include <hip/hip_bf16.h>

typedef __attribute__((ext_vector_type(8))) short bf16x8;
typedef __attribute__((ext_vector_type(4))) float f32x4;

static __device__ __forceinline__ void stf(float* p, size_t i, float v) { p[i] = v; }
static __device__ __forceinline__ void stf(__hip_bfloat16* p, size_t i, float v) { p[i] = __float2bfloat16(v); }

static __device__ __forceinline__ void gload_lds16(const void* g, void* l) {
  __builtin_amdgcn_global_load_lds((const __attribute__((address_space(1))) void*)g,
                                   (__attribute__((address_space(3))) void*)l, 16, 0, 0);
}

// ---------- weight transpose + bf16 convert: W[K][N] f32 -> WT[N][K] bf16 ----------
__global__ void wt_kernel(const float* __restrict__ W, __hip_bfloat16* __restrict__ WT, int K, int N) {
  __shared__ float tile[32][33];
  const int kb = blockIdx.y * 32, nb = blockIdx.x * 32;
  const int tx = threadIdx.x & 31, ty = threadIdx.x >> 5;
#pragma unroll
  for (int i = 0; i < 4; ++i)
    tile[ty + i * 8][tx] = W[(size_t)(kb + ty + i * 8) * N + nb + tx];
  __syncthreads();
#pragma unroll
  for (int i = 0; i < 4; ++i)
    WT[(size_t)(nb + ty + i * 8) * K + kb + tx] = __float2bfloat16(tile[tx][ty + i * 8]);
}

// ---------- conv prep ----------
__global__ void convprep_kernel(const float* __restrict__ w, const float* __restrict__ bng,
                                const float* __restrict__ bnb, const float* __restrict__ bnm,
                                const float* __restrict__ bnv, float* __restrict__ wT,
                                float* __restrict__ st) {
  const int i = blockIdx.x * 256 + threadIdx.x;
  if (i < 576 * 9) {
    const int t = i / 576, c = i - t * 576;
    wT[i] = w[c * 9 + t];
  }
  if (i < 576) {
    const float s = rsqrtf(bnv[i] + 1e-5f) * bng[i];
    st[i] = s;
    st[576 + i] = bnb[i] - bnm[i] * s;
  }
}

// ---------- fused LN -> bf16 ----------
__global__ void ln_bf16_kernel(const float* __restrict__ x, const float* __restrict__ g,
                               const float* __restrict__ b, __hip_bfloat16* __restrict__ y) {
  const int row = blockIdx.x * 4 + (threadIdx.x >> 6);
  const int lane = threadIdx.x & 63;
  const float* p = x + (size_t)row * 576;
  float vals[9];
  float s = 0.f, ss = 0.f;
#pragma unroll
  for (int i = 0; i < 9; ++i) {
    float v = p[lane + i * 64];
    vals[i] = v; s += v; ss += v * v;
  }
#pragma unroll
  for (int o = 32; o; o >>= 1) { s += __shfl_down(s, o); ss += __shfl_down(ss, o); }
  s = __shfl(s, 0); ss = __shfl(ss, 0);
  const float m = s * (1.f / 576.f);
  const float rstd = rsqrtf(ss * (1.f / 576.f) - m * m + 1e-5f);
  __hip_bfloat16* q = y + (size_t)row * 576;
#pragma unroll
  for (int i = 0; i < 9; ++i) {
    const int c = lane + i * 64;
    q[c] = __float2bfloat16((vals[i] - m) * rstd * g[c] + b[c]);
  }
}

// ---------- MFMA GEMM, high-occupancy: 128x64 tile, BK=32, 24KB LDS, 6 blk/CU ----------
// Swizzle f(row) = (row>>1)&3 (was row&3 -> 4-way conflict, 1.2e7 extra cycles):
// read bank-start = 16*row + 4*(l4^f(row)) mod 32 hits each of 8 starts exactly
// 2x over 16 consecutive rows -> 2-way aliasing = free (m136). Same involution
// applied on the staging (global-source) side -> mapping unchanged (rule #21).
// EPI: 0 none, 1 +res, 2 exact GELU
template <int EPI, typename TO>
__global__ __launch_bounds__(256, 6) void gemm_bt(
    const __hip_bfloat16* __restrict__ A, const __hip_bfloat16* __restrict__ BT,
    const float* __restrict__ bias, const float* __restrict__ res, TO* __restrict__ C,
    int M, int N, int K) {
  __shared__ __hip_bfloat16 sA[2][128 * 32];
  __shared__ __hip_bfloat16 sB[2][64 * 32];
  const int t = threadIdx.x;
  const int lane = t & 63;
  const int w = t >> 6;
  const int nwg = gridDim.x;
  const int qq = nwg >> 3, r = nwg & 7;
  const int xcd = blockIdx.x & 7, lidx = blockIdx.x >> 3;
  const int wgid = (xcd < r ? xcd * (qq + 1) : r * (qq + 1) + (xcd - r) * qq) + lidx;
  const int nx = N >> 6;
  const int bm = (wgid / nx) * 128, bn = (wgid % nx) * 64;
  const int wm = (w >> 1) * 64, wn = (w & 1) * 32;
  const int l15 = lane & 15, l4 = lane >> 4;
  const int wave_base = t & ~63;

  f32x4 acc[4][2];
#pragma unroll
  for (int mi = 0; mi < 4; ++mi)
#pragma unroll
    for (int ni = 0; ni < 2; ++ni) acc[mi][ni] = (f32x4){0.f, 0.f, 0.f, 0.f};

  auto stage = [&](int buf, int k0) {
#pragma unroll
    for (int i = 0; i < 2; ++i) {
      const int slot = i * 256 + t;
      const int row = slot >> 2, kst = slot & 3;
      const int ksrc = kst ^ ((row >> 1) & 3);
      gload_lds16(A + (size_t)(bm + row) * K + k0 + ksrc * 8,
                  sA[buf] + (i * 256 + wave_base) * 8);
    }
    {
      const int row = t >> 2, kst = t & 3;
      const int ksrc = kst ^ ((row >> 1) & 3);
      gload_lds16(BT + (size_t)(bn + row) * K + k0 + ksrc * 8,
                  sB[buf] + wave_base * 8);
    }
  };

  auto compute = [&](int buf) {
    bf16x8 a[4], b[2];
#pragma unroll
    for (int mi = 0; mi < 4; ++mi) {
      const int row = wm + mi * 16 + l15;
      a[mi] = *(const bf16x8*)(&sA[buf][row * 32 + ((l4 ^ ((row >> 1) & 3)) * 8)]);
    }
#pragma unroll
    for (int ni = 0; ni < 2; ++ni) {
      const int row = wn + ni * 16 + l15;
      b[ni] = *(const bf16x8*)(&sB[buf][row * 32 + ((l4 ^ ((row >> 1) & 3)) * 8)]);
    }
#pragma unroll
    for (int mi = 0; mi < 4; ++mi)
#pragma unroll
      for (int ni = 0; ni < 2; ++ni)
        acc[mi][ni] = __builtin_amdgcn_mfma_f32_16x16x32_bf16(a[mi], b[ni], acc[mi][ni], 0, 0, 0);
  };

  const int nt = K >> 5;
  stage(0, 0);
  __syncthreads();
  int cur = 0;
  for (int tt = 0; tt < nt - 1; ++tt) {
    stage(cur ^ 1, (tt + 1) << 5);
    compute(cur);
    __syncthreads();
    cur ^= 1;
  }
  compute(cur);

#pragma unroll
  for (int mi = 0; mi < 4; ++mi) {
    const int mrow = bm + wm + mi * 16 + l4 * 4;
#pragma unroll
    for (int ni = 0; ni < 2; ++ni) {
      const int col = bn + wn + ni * 16 + l15;
      const float bv = bias[col];
#pragma unroll
      for (int r2 = 0; r2 < 4; ++r2) {
        const size_t idx = (size_t)(mrow + r2) * N + col;
        float v = acc[mi][ni][r2] + bv;
        if (EPI == 1) v += res[idx];
        if (EPI == 2) v = 0.5f * v * (1.0f + erff(v * 0.70710678118654752f));
        stf(C, idx, v);
      }
    }
  }
}

// ---------- MFMA windowed attention, low-LDS (R12 config, kept) ----------
__global__ __launch_bounds__(64) void attn_mfma_kernel(
    const __hip_bfloat16* __restrict__ qkv, const float* __restrict__ biases,
    __hip_bfloat16* __restrict__ o) {
  __shared__ __hip_bfloat16 sVT[32][72];
  __shared__ __hip_bfloat16 sP[64][72];

  const int wid  = blockIdx.x / 18;
  const int head = blockIdx.x - wid * 18;
  const int b  = wid >> 4;
  const int wi = wid & 15;
  const int wh = wi >> 2, wwc = wi & 3;
  const int lane = threadIdx.x;
  const int l15 = lane & 15, l4 = lane >> 4;

  auto growof = [&](int tkn) -> size_t {
    const int r = tkn / 7, c = tkn - r * 7;
    return (size_t)b * 784 + (size_t)((wh * 7 + r) * 28 + wwc * 7 + c);
  };

  for (int idx = lane; idx < 49 * 4; idx += 64) {
    const int tkn = idx >> 2, part = idx & 3;
    const bf16x8 v = *(const bf16x8*)(qkv + growof(tkn) * 1728 + head * 96 + 64 + part * 8);
    const short* sv = (const short*)&v;
#pragma unroll
    for (int e = 0; e < 8; ++e)
      sVT[part * 8 + e][tkn] = *(const __hip_bfloat16*)&sv[e];
  }
  for (int idx = lane; idx < 32 * 15; idx += 64) {
    const int d = idx / 15, tt = 49 + (idx - d * 15);
    sVT[d][tt] = __float2bfloat16(0.0f);
  }

  bf16x8 aq[4], bk[4];
#pragma unroll
  for (int mi = 0; mi < 4; ++mi) {
    int tk = mi * 16 + l15; if (tk > 48) tk = 0;
    aq[mi] = *(const bf16x8*)(qkv + growof(tk) * 1728 + head * 96 + l4 * 8);
  }
#pragma unroll
  for (int ni = 0; ni < 4; ++ni) {
    int tk = ni * 16 + l15; if (tk > 48) tk = 0;
    bk[ni] = *(const bf16x8*)(qkv + growof(tk) * 1728 + head * 96 + 32 + l4 * 8);
  }

  f32x4 acc[4][4];
#pragma unroll
  for (int mi = 0; mi < 4; ++mi)
#pragma unroll
    for (int ni = 0; ni < 4; ++ni) acc[mi][ni] = (f32x4){0.f, 0.f, 0.f, 0.f};
#pragma unroll
  for (int mi = 0; mi < 4; ++mi)
#pragma unroll
    for (int ni = 0; ni < 4; ++ni)
      acc[mi][ni] = __builtin_amdgcn_mfma_f32_16x16x32_bf16(aq[mi], bk[ni], acc[mi][ni], 0, 0, 0);

  const float scale = 0.17677669529663687f;
  const float* btab = biases + head * 49;
#pragma unroll
  for (int mi = 0; mi < 4; ++mi) {
#pragma unroll
    for (int rr = 0; rr < 4; ++rr) {
      const int i = mi * 16 + l4 * 4 + rr;
      const int ic = i < 49 ? i : 0;
      const int ri = ic / 7, ci = ic - ri * 7;
      float s[4];
#pragma unroll
      for (int ni = 0; ni < 4; ++ni) {
        const int j = ni * 16 + l15;
        if (j < 49) {
          const int rj = j / 7, cj = j - rj * 7;
          s[ni] = acc[mi][ni][rr] * scale + btab[__builtin_abs(ri - rj) * 7 + __builtin_abs(ci - cj)];
        } else {
          s[ni] = -1e30f;
        }
      }
      float m = fmaxf(fmaxf(s[0], s[1]), fmaxf(s[2], s[3]));
#pragma unroll
      for (int d = 1; d < 16; d <<= 1) m = fmaxf(m, __shfl_xor(m, d));
      float sum = 0.f;
#pragma unroll
      for (int ni = 0; ni < 4; ++ni) { s[ni] = __expf(s[ni] - m); sum += s[ni]; }
#pragma unroll
      for (int d = 1; d < 16; d <<= 1) sum += __shfl_xor(sum, d);
      const float inv = 1.0f / sum;
#pragma unroll
      for (int ni = 0; ni < 4; ++ni)
        sP[i][ni * 16 + l15] = __float2bfloat16(s[ni] * inv);
    }
  }
  __syncthreads();

  f32x4 oacc[4][2];
#pragma unroll
  for (int mi = 0; mi < 4; ++mi)
#pragma unroll
    for (int ni = 0; ni < 2; ++ni) oacc[mi][ni] = (f32x4){0.f, 0.f, 0.f, 0.f};
#pragma unroll
  for (int kb = 0; kb < 2; ++kb) {
    bf16x8 ap[4], bv[2];
#pragma unroll
    for (int mi = 0; mi < 4; ++mi) ap[mi] = *(const bf16x8*)&sP[mi * 16 + l15][kb * 32 + l4 * 8];
#pragma unroll
    for (int ni = 0; ni < 2; ++ni) bv[ni] = *(const bf16x8*)&sVT[ni * 16 + l15][kb * 32 + l4 * 8];
#pragma unroll
    for (int mi = 0; mi < 4; ++mi)
#pragma unroll
      for (int ni = 0; ni < 2; ++ni)
        oacc[mi][ni] = __builtin_amdgcn_mfma_f32_16x16x32_bf16(ap[mi], bv[ni], oacc[mi][ni], 0, 0, 0);
  }

#pragma unroll
  for (int mi = 0; mi < 4; ++mi) {
#pragma unroll
    for (int rr = 0; rr < 4; ++rr) {
      const int i = mi * 16 + l4 * 4 + rr;
      if (i < 49) {
        const size_t grow = growof(i);
#pragma unroll
        for (int ni = 0; ni < 2; ++ni)
          o[grow * 576 + head * 32 + ni * 16 + l15] = __float2bfloat16(oacc[mi][ni][rr]);
      }
    }
  }
}

// ---------- depthwise 3x3 conv + folded BN, float4 over channels ----------
__global__ void conv_bn_kernel(const float* __restrict__ x1, const float* __restrict__ wT,
                               const float* __restrict__ st, float* __restrict__ x2) {
  const size_t total = (size_t)32 * 784 * 144;
  const size_t idx = (size_t)blockIdx.x * 256 + threadIdx.x;
  if (idx >= total) return;
  const int c4 = (int)(idx % 144);
  const size_t p = idx / 144;
  const int pix = (int)(p % 784);
  const int b = (int)(p / 784);
  const int i = pix / 28, j = pix - (pix / 28) * 28;
  const int c = c4 * 4;
  f32x4 acc = (f32x4){0.f, 0.f, 0.f, 0.f};
#pragma unroll
  for (int dh = -1; dh <= 1; ++dh) {
#pragma unroll
    for (int dw = -1; dw <= 1; ++dw) {
      const int ii = i + dh, jj = j + dw;
      if (ii >= 0 && ii < 28 && jj >= 0 && jj < 28) {
        const f32x4 v = *(const f32x4*)&x1[((size_t)b * 784 + ii * 28 + jj) * 576 + c];
        const f32x4 wv = *(const f32x4*)&wT[((dh + 1) * 3 + (dw + 1)) * 576 + c];
        acc += v * wv;
      }
    }
  }
  const f32x4 s = *(const f32x4*)&st[c];
  const f32x4 tt = *(const f32x4*)&st[576 + c];
  *(f32x4*)&x2[((size_t)b * 784 + pix) * 576 + c] = acc * s + tt;
}

// ---------- launch ----------
extern "C" void kernel_launch(void* const* d_in, const int* in_sizes, int n_in,
                              void* d_out, int out_size, void* d_ws, size_t ws_size,
                              hipStream_t stream) {
  (void)in_sizes; (void)n_in; (void)out_size; (void)ws_size;
  const float* x      = (const float*)d_in[0];
  const float* ln1g   = (const float*)d_in[1];
  const float* ln1b   = (const float*)d_in[2];
  const float* qkv_w  = (const float*)d_in[3];
  const float* qkv_b  = (const float*)d_in[4];
  const float* biases = (const float*)d_in[5];
  const float* proj_w = (const float*)d_in[6];
  const float* proj_b = (const float*)d_in[7];
  const float* conv_w = (const float*)d_in[8];
  const float* bng    = (const float*)d_in[9];
  const float* bnb    = (const float*)d_in[10];
  const float* bnm    = (const float*)d_in[11];
  const float* bnv    = (const float*)d_in[12];
  const float* ln2g   = (const float*)d_in[13];
  const float* ln2b   = (const float*)d_in[14];
  const float* fc1_w  = (const float*)d_in[15];
  const float* fc1_b  = (const float*)d_in[16];
  const float* fc2_w  = (const float*)d_in[17];
  const float* fc2_b  = (const float*)d_in[18];
  float* out = (float*)d_out;

  const int M = 25088;
  char* ws = (char*)d_ws;
  float* x2 = (float*)ws;
  char* regB = ws + 57802752;
  __hip_bfloat16* qkvb = (__hip_bfloat16*)regB;
  float*          x1   = (float*)regB;
  __hip_bfloat16* hm   = (__hip_bfloat16*)regB;
  char* regC = ws + 173408256;
  __hip_bfloat16* xn1  = (__hip_bfloat16*)regC;
  __hip_bfloat16* obuf = (__hip_bfloat16*)regC;
  __hip_bfloat16* xn2  = (__hip_bfloat16*)regC;
  char* regD = ws + 202309632;
  __hip_bfloat16* qkvT = (__hip_bfloat16*)regD;
  __hip_bfloat16* projT = (__hip_bfloat16*)(regD + 1990656);
  __hip_bfloat16* fc1T  = (__hip_bfloat16*)(regD + 1990656 + 663552);
  __hip_bfloat16* fc2T  = (__hip_bfloat16*)(regD + 1990656 + 663552 + 2654208);
  float* convT = (float*)(ws + 210272256);
  float* convST = convT + 9 * 576;

  // weight prep
  wt_kernel<<<dim3(1728 / 32, 576 / 32), 256, 0, stream>>>(qkv_w, qkvT, 576, 1728);
  wt_kernel<<<dim3(576 / 32, 576 / 32), 256, 0, stream>>>(proj_w, projT, 576, 576);
  wt_kernel<<<dim3(2304 / 32, 576 / 32), 256, 0, stream>>>(fc1_w, fc1T, 576, 2304);
  wt_kernel<<<dim3(576 / 32, 2304 / 32), 256, 0, stream>>>(fc2_w, fc2T, 2304, 576);
  convprep_kernel<<<(576 * 9 + 255) / 256, 256, 0, stream>>>(conv_w, bng, bnb, bnm, bnv, convT, convST);

  // 1. xn1 = LN1(x) bf16
  ln_bf16_kernel<<<M / 4, 256, 0, stream>>>(x, ln1g, ln1b, xn1);
  // 2. qkv = xn1 @ qkv_w + qkv_b (bf16 out); grid 196 x 27
  gemm_bt<0, __hip_bfloat16><<<196 * 27, 256, 0, stream>>>(xn1, qkvT, qkv_b, nullptr, qkvb, M, 1728, 576);
  // 3. attention (low-LDS MFMA)
  attn_mfma_kernel<<<512 * 18, 64, 0, stream>>>(qkvb, biases, obuf);
  // 4. x1 = x + (o @ proj_w + proj_b); grid 196 x 9
  gemm_bt<1, float><<<196 * 9, 256, 0, stream>>>(obuf, projT, proj_b, x, x1, M, 576, 576);
  // 5. x2 = BN(dwconv(x1))
  conv_bn_kernel<<<(32 * 784 * 144 + 255) / 256, 256, 0, stream>>>(x1, convT, convST, x2);
  // 6. xn2 = LN2(x2) bf16
  ln_bf16_kernel<<<M / 4, 256, 0, stream>>>(x2, ln2g, ln2b, xn2);
  // 7. hm = gelu(xn2 @ fc1_w + fc1_b) bf16; grid 196 x 36
  gemm_bt<2, __hip_bfloat16><<<196 * 36, 256, 0, stream>>>(xn2, fc1T, fc1_b, nullptr, hm, M, 2304, 576);
  // 8. out = x2 + (hm @ fc2_w + fc2_b); grid 196 x 9
  gemm_bt<1, float><<<196 * 9, 256, 0, stream>>>(hm, fc2T, fc2_b, x2, out, M, 576, 2304);
}